// Round 14
// baseline (5759.958 us; speedup 1.0000x reference)
//
#include <hip/hip_runtime.h>
#include <math.h>

// RNN: L=512, B=128, D=512, H=1024, fp32 in/out.
//   xproj = x @ Wx^T + bx -> d_out;  h_t = tanh(xp_t + h_{t-1} @ Wh^T) in place.
// Precision: split-bf16 (hi+lo), 3 MFMAs per product => ~fp32 accuracy.
// Round 14 = R12 (tag-fused exchange, 16x32 tiles — protocol PASSED, perf
// killed by compiler rematerializing the 64-VGPR B-slice into per-step L2
// reloads, VGPR_Count=68) + opaque-asm KEEP-ALIVE on every B fragment:
// asm("" : "+v"(frag)) makes remat illegal -> B stays register-resident.
// Expected tell: VGPR_Count >= 140. Serial path/step becomes ONE L3 hop
// (tagged A-burst) + unpack + 24 MFMA + LDS reduce + tagged store.
// R13 lesson folded in: sc1 == sc0sc1 in behavior & cost; keep sc0 sc1.

#define L_SEQ 512
#define B_SZ  128
#define H_SZ  1024
#define BH    (B_SZ * H_SZ)   // 131072

typedef __bf16 bf16x8 __attribute__((ext_vector_type(8)));
typedef float  f32x4  __attribute__((ext_vector_type(4)));
typedef unsigned int uint;
typedef uint u32x4 __attribute__((ext_vector_type(4)));
typedef unsigned short ushort;

union V8 { bf16x8 b; ushort u[8]; uint w[4]; };

__device__ __forceinline__ ushort f2bf(float f) {
  uint u = __float_as_uint(f);
  u += 0x7FFFu + ((u >> 16) & 1u);   // round-to-nearest-even
  return (ushort)(u >> 16);
}
__device__ __forceinline__ float bf2f(ushort s) {
  return __uint_as_float(((uint)s) << 16);
}

// tanh(x) = 1 - 2/(e^{2x}+1); v_exp_f32(2^x) + v_rcp_f32. Saturates right.
__device__ __forceinline__ float fast_tanh(float x) {
  float e;
  asm("v_exp_f32 %0, %1" : "=v"(e) : "v"(x * 2.885390081777927f));
  float r;
  asm("v_rcp_f32 %0, %1" : "=v"(r) : "v"(e + 1.0f));
  return 1.0f - 2.0f * r;
}

// Agent-scope (sc0 sc1): bypass L1+L2, coherent at the L3 point. PROVEN.
__device__ __forceinline__ void ldg16_sc(u32x4& d, const uint* p) {
  asm volatile("global_load_dwordx4 %0, %1, off sc0 sc1"
               : "=v"(d) : "v"(p) : "memory");
}
__device__ __forceinline__ void stg4_sc(uint* p, uint v) {
  asm volatile("global_store_dword %0, %1, off sc0 sc1"
               :: "v"(p), "v"(v) : "memory");
}

// ---- d_ws layout (ushort element indices) ----
#define WS_WHH 0            // [1024][1024]
#define WS_WHL 1048576      // [1024][1024]
#define WS_WXH 2097152      // [1024][512]
#define WS_WXL 2621440      // [1024][512]
#define WS_HBT 3145728      // u32 [2 planes][BH] packed {hi,lo14,tag2} = 1 MB

// Split fp32 weights into bf16 hi + lo(residual); zero the tagged h planes.
__global__ void split_kernel(const float* __restrict__ Wh,
                             const float* __restrict__ Wx,
                             ushort* __restrict__ ws,
                             uint* __restrict__ hbt) {
  const int gid = blockIdx.x * blockDim.x + threadIdx.x;
  if (gid < 2 * BH) hbt[gid] = 0u;           // tag 0 = never-valid
  const int total = 1048576 + 524288;
  for (int i = gid; i < total; i += gridDim.x * blockDim.x) {
    const float* src; ushort *dh, *dl; int j;
    if (i < 1048576) { src = Wh; dh = ws + WS_WHH; dl = ws + WS_WHL; j = i; }
    else             { src = Wx; dh = ws + WS_WXH; dl = ws + WS_WXL; j = i - 1048576; }
    float v = src[j];
    ushort h = f2bf(v);
    dh[j] = h;
    dl[j] = f2bf(v - bf2f(h));
  }
}

// xproj: out[m][n] = sum_d x[m][d]*Wx[n][d] + bx[n]  (unchanged)
__global__ __launch_bounds__(256) void xproj_kernel(
    const float* __restrict__ x,             // [65536][512]
    const ushort* __restrict__ wxh,          // [1024][512]
    const ushort* __restrict__ wxl,
    const float* __restrict__ bx,            // [1024]
    float* __restrict__ out)                 // [65536][1024]
{
  const int bid = blockIdx.x;
  const int bn = bid & 15;
  const int bm = bid >> 4;
  const int tid = threadIdx.x;
  const int w = tid >> 6, l = tid & 63;
  const int wm = w & 1, wn = w >> 1;
  const int lr = l & 15, lk = (l >> 4) * 8;
  const int mbase = bm * 128 + wm * 64;
  const int nbase = bn * 64 + wn * 32;

  f32x4 acc[4][2] = {};

  for (int k0 = 0; k0 < 512; k0 += 32) {
    bf16x8 ah[4], al[4], bh[2], bl[2];
#pragma unroll
    for (int i = 0; i < 4; ++i) {
      const float* ap = x + (size_t)(mbase + i * 16 + lr) * 512 + k0 + lk;
      float4 v0 = *reinterpret_cast<const float4*>(ap);
      float4 v1 = *reinterpret_cast<const float4*>(ap + 4);
      float vv[8] = {v0.x, v0.y, v0.z, v0.w, v1.x, v1.y, v1.z, v1.w};
      V8 hh, ll;
#pragma unroll
      for (int e = 0; e < 8; ++e) {
        ushort hb = f2bf(vv[e]);
        hh.u[e] = hb;
        ll.u[e] = f2bf(vv[e] - bf2f(hb));
      }
      ah[i] = hh.b; al[i] = ll.b;
    }
#pragma unroll
    for (int j = 0; j < 2; ++j) {
      size_t boff = (size_t)(nbase + j * 16 + lr) * 512 + k0 + lk;
      bh[j] = *reinterpret_cast<const bf16x8*>(wxh + boff);
      bl[j] = *reinterpret_cast<const bf16x8*>(wxl + boff);
    }
#pragma unroll
    for (int i = 0; i < 4; ++i)
#pragma unroll
      for (int j = 0; j < 2; ++j) {
        acc[i][j] = __builtin_amdgcn_mfma_f32_16x16x32_bf16(ah[i], bh[j], acc[i][j], 0, 0, 0);
        acc[i][j] = __builtin_amdgcn_mfma_f32_16x16x32_bf16(ah[i], bl[j], acc[i][j], 0, 0, 0);
        acc[i][j] = __builtin_amdgcn_mfma_f32_16x16x32_bf16(al[i], bh[j], acc[i][j], 0, 0, 0);
      }
  }

#pragma unroll
  for (int j = 0; j < 2; ++j) {
    int n = nbase + j * 16 + lr;
    float bxv = bx[n];
#pragma unroll
    for (int i = 0; i < 4; ++i)
#pragma unroll
      for (int r = 0; r < 4; ++r) {
        int m = mbase + i * 16 + (l >> 4) * 4 + r;
        out[(size_t)m * 1024 + n] = acc[i][j][r] + bxv;
      }
  }
}

// Persistent recurrence, tag-fused. 256 WGs x 512 thr (8 waves).
// WG (g = bid&7, c = bid>>3): rows [g*16,+16) x cols [c*32,+32), all steps.
// Wave w: K-slice [w*128,+128) (4 chunks of 32). B register-resident,
// ENFORCED by opaque-asm keep-alive (R12's defect: compiler remat'd B into
// per-step reloads at VGPR_Count=68 despite a 256-VGPR budget).
// Per step: poll+burst A (retry stale only) -> unpack -> 24 MFMA -> LDS
// partials (parity dbuf) -> 1 sync -> reduce + tanh -> tagged 4B h store.
// Plane safety (verified by R12 pass): a WG reaches step t+2 only after all
// group WGs stored t+1, which follows their consumption of plane t; tags
// {1,2,3} x plane parity disambiguate skew<=1; tag 0 = zero-init sentinel.
__global__ __launch_bounds__(512, 2) void rnn_persistent(
    const ushort* __restrict__ whh,  // [1024][1024]
    const ushort* __restrict__ whl,
    uint* __restrict__ hbt,          // [2 planes][BH] packed {hi,lo14,tag2}
    float* __restrict__ out)         // [512][BH] (xproj in, h out)
{
  __shared__ float part[2][8][544];  // [parity][wave][col*17+row], 34816 B
  const int wg = blockIdx.x;         // 0..255
  const int g  = wg & 7;             // row-group (16 rows) — closed pod
  const int c  = wg >> 3;            // col-WG 0..31
  const int tid = threadIdx.x;
  const int w = tid >> 6, l = tid & 63;
  const int lr = l & 15, lq = l >> 4;

  // ---- B preload (whole sequence): 2 col-tiles x 4 chunks x hi/lo. ----
  bf16x8 vBh[2][4], vBl[2][4];
#pragma unroll
  for (int ct = 0; ct < 2; ++ct)
#pragma unroll
    for (int ck = 0; ck < 4; ++ck) {
      size_t a = (size_t)(c * 32 + ct * 16 + lr) * 1024 + w * 128 + ck * 32 + lq * 8;
      vBh[ct][ck] = *reinterpret_cast<const bf16x8*>(whh + a);
      vBl[ct][ck] = *reinterpret_cast<const bf16x8*>(whl + a);
    }
  // KEEP-ALIVE: value passes through opaque asm -> rematerialization of the
  // loads is illegal -> B must stay in VGPRs across the whole t-loop.
#pragma unroll
  for (int ct = 0; ct < 2; ++ct)
#pragma unroll
    for (int ck = 0; ck < 4; ++ck) {
      asm volatile("" : "+v"(vBh[ct][ck]));
      asm volatile("" : "+v"(vBl[ct][ck]));
    }

  // A-frag base: row g*16+lr, k = w*128 + lq*8 (+ck*32), u32 elements.
  const size_t aoff = (size_t)(g * 16 + lr) * 1024 + w * 128 + lq * 8;

  // Epilogue: one output elem/thread over the 16x32 tile.
  const int erow = tid & 15, ecol = tid >> 4;
  const size_t oidx = (size_t)(g * 16 + erow) * 1024 + c * 32 + ecol;

  // ---- t = 0: h_0 = tanh(xp_0); tagged store (tag=1) into plane 0. ----
  {
    float h = fast_tanh(out[oidx]);
    out[oidx] = h;
    ushort hh = f2bf(h);
    ushort ll = f2bf(h - bf2f(hh));
    stg4_sc(hbt + oidx, ((uint)hh << 16) | ((uint)ll & 0xFFFCu) | 1u);
  }

  for (int t = 1; t < L_SEQ; ++t) {
    const uint tagv  = (uint)((t - 1) % 3) + 1u;  // expected on h_{t-1}
    const uint mytag = (uint)(t % 3) + 1u;        // published with h_t
    const uint* pb = hbt + (size_t)((t - 1) & 1) * BH + aoff;
    const float xpv = out[(size_t)t * BH + oidx]; // plain cached prefetch

    // ---- Poll + burst: initial 8 dwordx4; retry ONLY stale chunks. ----
    u32x4 d[8];
#pragma unroll
    for (int ck = 0; ck < 4; ++ck) {
      ldg16_sc(d[2 * ck],     pb + ck * 32);
      ldg16_sc(d[2 * ck + 1], pb + ck * 32 + 4);
    }
    asm volatile("s_waitcnt vmcnt(0)" ::: "memory");
    for (uint spin = 0; spin < (1u << 20); ++spin) {
      bool ok[4]; bool allok = true;
#pragma unroll
      for (int ck = 0; ck < 4; ++ck) {
        uint xo = (d[2*ck][0] ^ tagv) | (d[2*ck][1] ^ tagv) |
                  (d[2*ck][2] ^ tagv) | (d[2*ck][3] ^ tagv) |
                  (d[2*ck+1][0] ^ tagv) | (d[2*ck+1][1] ^ tagv) |
                  (d[2*ck+1][2] ^ tagv) | (d[2*ck+1][3] ^ tagv);
        ok[ck] = ((xo & 3u) == 0u);
        allok = allok && ok[ck];
      }
      if (__all((int)allok)) break;
      __builtin_amdgcn_s_sleep(2);
#pragma unroll
      for (int ck = 0; ck < 4; ++ck) {
        if (!ok[ck]) {                       // exec-masked per-lane reload
          ldg16_sc(d[2 * ck],     pb + ck * 32);
          ldg16_sc(d[2 * ck + 1], pb + ck * 32 + 4);
        }
      }
      asm volatile("s_waitcnt vmcnt(0)" ::: "memory");
    }
    __builtin_amdgcn_sched_barrier(0);       // rule #18: nothing hoists

    // ---- Unpack payloads -> A hi/lo frags (no LDS). ----
    bf16x8 vAh[4], vAl[4];
#pragma unroll
    for (int ck = 0; ck < 4; ++ck) {
      V8 hh, ll;
#pragma unroll
      for (int i = 0; i < 2; ++i) {
        const u32x4 p = d[2 * ck + i];
        hh.w[2*i]   = (p[0] >> 16) | (p[1] & 0xFFFF0000u);
        hh.w[2*i+1] = (p[2] >> 16) | (p[3] & 0xFFFF0000u);
        ll.w[2*i]   = (p[0] & 0xFFFCu) | ((p[1] & 0xFFFCu) << 16);
        ll.w[2*i+1] = (p[2] & 0xFFFCu) | ((p[3] & 0xFFFCu) << 16);
      }
      vAh[ck] = hh.b; vAl[ck] = ll.b;
    }

    // ---- MFMA: 2 col-tiles x 4 chunks x 3 splits = 24. ----
    f32x4 acc0 = {0.f, 0.f, 0.f, 0.f};
    f32x4 acc1 = {0.f, 0.f, 0.f, 0.f};
#pragma unroll
    for (int ck = 0; ck < 4; ++ck) {
      acc0 = __builtin_amdgcn_mfma_f32_16x16x32_bf16(vAh[ck], vBh[0][ck], acc0, 0, 0, 0);
      acc1 = __builtin_amdgcn_mfma_f32_16x16x32_bf16(vAh[ck], vBh[1][ck], acc1, 0, 0, 0);
      acc0 = __builtin_amdgcn_mfma_f32_16x16x32_bf16(vAh[ck], vBl[0][ck], acc0, 0, 0, 0);
      acc1 = __builtin_amdgcn_mfma_f32_16x16x32_bf16(vAh[ck], vBl[1][ck], acc1, 0, 0, 0);
      acc0 = __builtin_amdgcn_mfma_f32_16x16x32_bf16(vAl[ck], vBh[0][ck], acc0, 0, 0, 0);
      acc1 = __builtin_amdgcn_mfma_f32_16x16x32_bf16(vAl[ck], vBh[1][ck], acc1, 0, 0, 0);
    }

    // ---- Partials -> LDS (parity buffer). col = lane&15, row = lq*4+r. ----
    float* pp = &part[t & 1][w][0];
#pragma unroll
    for (int r = 0; r < 4; ++r) {
      pp[(lr) * 17      + lq * 4 + r] = acc0[r];   // cols c*32 + [0,16)
      pp[(16 + lr) * 17 + lq * 4 + r] = acc1[r];   // cols c*32 + [16,32)
    }
    __syncthreads();                         // the ONE sync per step

    // ---- Reduce 8 waves, tanh, tagged store. ----
    float s = 0.f;
#pragma unroll
    for (int q = 0; q < 8; ++q) s += part[t & 1][q][ecol * 17 + erow];
    float h = fast_tanh(s + xpv);
    out[(size_t)t * BH + oidx] = h;          // plain cached fp32 out
    ushort hh = f2bf(h);
    ushort ll = f2bf(h - bf2f(hh));
    stg4_sc(hbt + (size_t)(t & 1) * BH + oidx,
            ((uint)hh << 16) | ((uint)ll & 0xFFFCu) | mytag);
  }
}

extern "C" void kernel_launch(void* const* d_in, const int* in_sizes, int n_in,
                              void* d_out, int out_size, void* d_ws, size_t ws_size,
                              hipStream_t stream) {
  const float* x  = (const float*)d_in[0];   // [512][128][512]
  const float* Wx = (const float*)d_in[1];   // [1024][512]
  const float* bx = (const float*)d_in[2];   // [1024]
  const float* Wh = (const float*)d_in[3];   // [1024][1024]
  float* out = (float*)d_out;                // [512][128][1024]
  ushort* ws = (ushort*)d_ws;

  ushort* whh = ws + WS_WHH;
  ushort* whl = ws + WS_WHL;
  ushort* wxh = ws + WS_WXH;
  ushort* wxl = ws + WS_WXL;
  uint*   hbt = (uint*)(ws + WS_HBT);        // [2][BH] packed h + tag

  split_kernel<<<dim3(2048), dim3(256), 0, stream>>>(Wh, Wx, ws, hbt);
  xproj_kernel<<<dim3(8192), dim3(256), 0, stream>>>(x, wxh, wxl, bx, out);
  rnn_persistent<<<dim3(256), dim3(512), 0, stream>>>(whh, whl, hbt, out);
}

// Round 16
// 5004.567 us; speedup vs baseline: 1.1509x; 1.1509x over previous
//
#include <hip/hip_runtime.h>
#include <math.h>

// RNN: L=512, B=128, D=512, H=1024, fp32 in/out.
//   xproj = x @ Wx^T + bx -> d_out;  h_t = tanh(xp_t + h_{t-1} @ Wh^T) in place.
// Precision: split-bf16 (hi+lo), 3 MFMAs per product => ~fp32 accuracy.
// Round 16 = R15 fusion retried with the deadlock precondition FIXED.
// R15 post-mortem: __launch_bounds__(512,2) allows 256-VGPR alloc -> 1
// block/CU -> 256 recurrence blocks camp on ALL slots -> xproj never runs ->
// every xp-gate escapes (131s pytest, absmax 4.8). Fix:
//   __launch_bounds__(512,4) caps VGPR at 128 -> 2 blocks/CU GUARANTEED
//   (LDS 34.8KB x2 = 70KB <= 160KB; 1024 thr <= 2048). R13's recurrence only
//   ever used 60-68 VGPRs, so the cap binds nothing on the critical path.
// Conservatism: recurrence protocol is EXACTLY R13's proven per-WG-flag form
// (fusion is the only variable). xp read AFTER the gate via sc0sc1.
// Blocks 0..255: recurrence. Blocks 256..8447: xproj tile (bm == timestep).

#define L_SEQ 512
#define B_SZ  128
#define H_SZ  1024
#define BH    (B_SZ * H_SZ)   // 131072

typedef __bf16 bf16x8 __attribute__((ext_vector_type(8)));
typedef float  f32x4  __attribute__((ext_vector_type(4)));
typedef unsigned int uint;
typedef unsigned short ushort;

union V8 { bf16x8 b; ushort u[8]; uint w[4]; };

__device__ __forceinline__ ushort f2bf(float f) {
  uint u = __float_as_uint(f);
  u += 0x7FFFu + ((u >> 16) & 1u);   // round-to-nearest-even
  return (ushort)(u >> 16);
}
__device__ __forceinline__ float bf2f(ushort s) {
  return __uint_as_float(((uint)s) << 16);
}

// tanh(x) = 1 - 2/(e^{2x}+1); v_exp_f32(2^x) + v_rcp_f32. Saturates right.
__device__ __forceinline__ float fast_tanh(float x) {
  float e;
  asm("v_exp_f32 %0, %1" : "=v"(e) : "v"(x * 2.885390081777927f));
  float r;
  asm("v_rcp_f32 %0, %1" : "=v"(r) : "v"(e + 1.0f));
  return 1.0f - 2.0f * r;
}

// Agent-scope (sc0 sc1): bypass L1+L2, coherent at the L3 point. PROVEN (R8).
__device__ __forceinline__ void ldg16_sc(bf16x8& d, const ushort* p) {
  asm volatile("global_load_dwordx4 %0, %1, off sc0 sc1"
               : "=v"(d) : "v"(p) : "memory");
}
__device__ __forceinline__ void stg2_sc(ushort* p, uint v) {
  asm volatile("global_store_short %0, %1, off sc0 sc1"
               :: "v"(p), "v"(v) : "memory");
}
__device__ __forceinline__ void stg4_sc(uint* p, uint v) {
  asm volatile("global_store_dword %0, %1, off sc0 sc1"
               :: "v"(p), "v"(v) : "memory");
}

// ---- d_ws layout (ushort element indices) ----
#define WS_WHH 0            // [1024][1024]
#define WS_WHL 1048576      // [1024][1024]
#define WS_WXH 2097152      // [1024][512]
#define WS_WXL 2621440      // [1024][512]
#define WS_HB  3145728      // [2 parity][2 hi/lo][BH] ushort
#define WS_FLG 3670016      // u32: flags[4][64] then xpflags[512][16]

// Split fp32 weights into bf16 hi + lo(residual); zero WG + xp flags.
__global__ void split_kernel(const float* __restrict__ Wh,
                             const float* __restrict__ Wx,
                             ushort* __restrict__ ws,
                             uint* __restrict__ flg) {
  const int gid = blockIdx.x * blockDim.x + threadIdx.x;
  if (gid < 256 + 8192) flg[gid] = 0u;
  const int total = 1048576 + 524288;
  for (int i = gid; i < total; i += gridDim.x * blockDim.x) {
    const float* src; ushort *dh, *dl; int j;
    if (i < 1048576) { src = Wh; dh = ws + WS_WHH; dl = ws + WS_WHL; j = i; }
    else             { src = Wx; dh = ws + WS_WXH; dl = ws + WS_WXL; j = i - 1048576; }
    float v = src[j];
    ushort h = f2bf(v);
    dh[j] = h;
    dl[j] = f2bf(v - bf2f(h));
  }
}

// Fused kernel. Blocks 0..255: recurrence (R13 protocol verbatim + xp gate).
// Blocks 256..8447: one xproj tile each (bm = timestep, bn = 64-col block).
__global__ __launch_bounds__(512, 4) void fused_kernel(
    const float* __restrict__ x,     // [65536][512]
    const ushort* __restrict__ wxh,  // [1024][512]
    const ushort* __restrict__ wxl,
    const float* __restrict__ bx,    // [1024]
    const ushort* __restrict__ whh,  // [1024][1024]
    const ushort* __restrict__ whl,
    ushort* __restrict__ hb,         // [2 parity][2 hi/lo][BH]
    float* __restrict__ out,         // [512][BH] (xproj in, h out)
    uint* __restrict__ flags,        // [4][64] per-WG h flags
    uint* __restrict__ xpflags)      // [512][16] xp tile-ready flags
{
  __shared__ float lds[8 * 32 * 17]; // 17408 B (recurrence partials)
  const int bid = blockIdx.x;
  const int tid = threadIdx.x;

  if (bid >= 256) {
    // ================= xproj path (never waits) =================
    const int xb = bid - 256;
    const int bn = xb & 15;          // 16 col-blocks of 64
    const int bm = xb >> 4;          // M-block == timestep t
    const int w = tid >> 6, l = tid & 63;
    const int wm = w & 1, wn = w >> 1;           // 2(M) x 4(N) waves
    const int lr = l & 15, lk = (l >> 4) * 8;
    const int mbase = bm * 128 + wm * 64;
    const int nbase = bn * 64 + wn * 16;

    f32x4 acc[4] = {};
    for (int k0 = 0; k0 < 512; k0 += 32) {
      bf16x8 ah[4], al[4], bh, bl;
#pragma unroll
      for (int i = 0; i < 4; ++i) {
        const float* ap = x + (size_t)(mbase + i * 16 + lr) * 512 + k0 + lk;
        float4 v0 = *reinterpret_cast<const float4*>(ap);
        float4 v1 = *reinterpret_cast<const float4*>(ap + 4);
        float vv[8] = {v0.x, v0.y, v0.z, v0.w, v1.x, v1.y, v1.z, v1.w};
        V8 hh, ll;
#pragma unroll
        for (int e = 0; e < 8; ++e) {
          ushort hbv = f2bf(vv[e]);
          hh.u[e] = hbv;
          ll.u[e] = f2bf(vv[e] - bf2f(hbv));
        }
        ah[i] = hh.b; al[i] = ll.b;
      }
      size_t boff = (size_t)(nbase + lr) * 512 + k0 + lk;
      bh = *reinterpret_cast<const bf16x8*>(wxh + boff);
      bl = *reinterpret_cast<const bf16x8*>(wxl + boff);
#pragma unroll
      for (int i = 0; i < 4; ++i) {
        acc[i] = __builtin_amdgcn_mfma_f32_16x16x32_bf16(ah[i], bh, acc[i], 0, 0, 0);
        acc[i] = __builtin_amdgcn_mfma_f32_16x16x32_bf16(ah[i], bl, acc[i], 0, 0, 0);
        acc[i] = __builtin_amdgcn_mfma_f32_16x16x32_bf16(al[i], bh, acc[i], 0, 0, 0);
      }
    }
    // Epilogue: sc0sc1 stores (cross-XCD visible at L3) -> drain -> flag.
    const int n = nbase + lr;
    const float bxv = bx[n];
#pragma unroll
    for (int i = 0; i < 4; ++i)
#pragma unroll
      for (int r = 0; r < 4; ++r) {
        int m = mbase + i * 16 + (l >> 4) * 4 + r;
        stg4_sc((uint*)(out + (size_t)m * 1024 + n),
                __float_as_uint(acc[i][r] + bxv));
      }
    asm volatile("s_waitcnt vmcnt(0)" ::: "memory");
    __syncthreads();
    if (tid == 0) stg4_sc(xpflags + bm * 16 + bn, 1u);
    return;
  }

  // ============ recurrence path (R13 verbatim + xp gating) ============
  const int wg = bid;                // 0..255
  const int xc = wg & 7, yy = wg >> 3;
  const int mb = xc & 3;
  const int nb = ((xc >> 2) << 5) + yy;   // 0..63
  const int q = tid >> 6;            // k-slice 0..7
  const int l = tid & 63;
  const int lr = l & 15, lk = (l >> 4) * 8;
  const int kbase = q * 128 + lk;
  const int row0 = (l >> 4) * 4;

  // Wh fragments: registers for the whole sequence (8 frags = 32 VGPRs).
  const ushort* bph = whh + (size_t)(nb * 16 + lr) * 1024 + kbase;
  const ushort* bpl = whl + (size_t)(nb * 16 + lr) * 1024 + kbase;
  bf16x8 vBh[4], vBl[4];
#pragma unroll
  for (int kb = 0; kb < 4; ++kb) {
    vBh[kb] = *reinterpret_cast<const bf16x8*>(bph + kb * 32);
    vBl[kb] = *reinterpret_cast<const bf16x8*>(bpl + kb * 32);
  }

  const size_t aoff = (size_t)(mb * 32 + lr) * 1024 + kbase;
  const ushort* planeA0 = hb + aoff;
  const ushort* planeA1 = hb + 2 * BH + aoff;

  const int em = tid >> 4, en = tid & 15;
  const size_t eidx = (size_t)(mb * 32 + em) * 1024 + nb * 16 + en;

  const uint* gate_ptr = flags + (mb << 6) + (q << 3) + (l & 7);
  uint* my_flag = flags + (mb << 6) + nb;

  for (int t = 0; t < L_SEQ; ++t) {
    const uint* xpf_ptr = xpflags + t * 16 + (nb >> 2);
    float hval;

    if (t == 0) {
      // Gate on the xp tile only (uniform poll, bounded escape).
      for (uint spin = 0; spin < (1u << 20); ++spin) {
        uint xf;
        asm volatile("global_load_dword %0, %1, off sc0 sc1\n\t"
                     "s_waitcnt vmcnt(0)"
                     : "=v"(xf) : "v"(xpf_ptr) : "memory");
        if (__all((int)(xf != 0u))) break;
        __builtin_amdgcn_s_sleep(1);
      }
      __builtin_amdgcn_sched_barrier(0);
      uint xu;
      asm volatile("global_load_dword %0, %1, off sc0 sc1\n\t"
                   "s_waitcnt vmcnt(0)"
                   : "=v"(xu) : "v"((const uint*)(out + eidx)) : "memory");
      hval = fast_tanh(__uint_as_float(xu));
    } else {
      // Gate: 8 producer-WG flags (per-lane) AND this step's xp flag.
      const uint tgt = (uint)t;
      for (uint spin = 0; spin < (1u << 20); ++spin) {
        uint f, xf;
        asm volatile("global_load_dword %0, %2, off sc0 sc1\n\t"
                     "global_load_dword %1, %3, off sc0 sc1\n\t"
                     "s_waitcnt vmcnt(0)"
                     : "=&v"(f), "=&v"(xf)
                     : "v"(gate_ptr), "v"(xpf_ptr) : "memory");
        if (__all((int)((f >= tgt) & (xf != 0u)))) break;
        __builtin_amdgcn_s_sleep(1);
      }
      __builtin_amdgcn_sched_barrier(0);     // nothing drifts above the gate

      // xp element + A-burst in flight together, ONE drain.
      uint xu;
      asm volatile("global_load_dword %0, %1, off sc0 sc1"
                   : "=v"(xu)
                   : "v"((const uint*)(out + (size_t)t * BH + eidx)) : "memory");
      const ushort* ah = ((t - 1) & 1) ? planeA1 : planeA0;
      const ushort* al = ah + BH;
      bf16x8 vA0h[4], vA0l[4], vA1h[4], vA1l[4];
#pragma unroll
      for (int kb = 0; kb < 4; ++kb) {
        const int ko = kb * 32;
        ldg16_sc(vA0h[kb], ah + ko);
        ldg16_sc(vA0l[kb], al + ko);
        ldg16_sc(vA1h[kb], ah + 16 * 1024 + ko);
        ldg16_sc(vA1l[kb], al + 16 * 1024 + ko);
      }
      asm volatile("s_waitcnt vmcnt(0)" ::: "memory");
      __builtin_amdgcn_sched_barrier(0);     // rule #18: no consumer hoists

      f32x4 acc0 = {0.f, 0.f, 0.f, 0.f};
      f32x4 acc1 = {0.f, 0.f, 0.f, 0.f};
#pragma unroll
      for (int kb = 0; kb < 4; ++kb) {
        acc0 = __builtin_amdgcn_mfma_f32_16x16x32_bf16(vA0h[kb], vBh[kb], acc0, 0, 0, 0);
        acc1 = __builtin_amdgcn_mfma_f32_16x16x32_bf16(vA1h[kb], vBh[kb], acc1, 0, 0, 0);
        acc0 = __builtin_amdgcn_mfma_f32_16x16x32_bf16(vA0h[kb], vBl[kb], acc0, 0, 0, 0);
        acc1 = __builtin_amdgcn_mfma_f32_16x16x32_bf16(vA1h[kb], vBl[kb], acc1, 0, 0, 0);
        acc0 = __builtin_amdgcn_mfma_f32_16x16x32_bf16(vA0l[kb], vBh[kb], acc0, 0, 0, 0);
        acc1 = __builtin_amdgcn_mfma_f32_16x16x32_bf16(vA1l[kb], vBh[kb], acc1, 0, 0, 0);
      }

      // Partials -> LDS. C/D layout: col = lane&15, row = (lane>>4)*4 + r.
#pragma unroll
      for (int r = 0; r < 4; ++r) {
        lds[q * 544 + (row0 + r) * 17 + lr]      = acc0[r];
        lds[q * 544 + (16 + row0 + r) * 17 + lr] = acc1[r];
      }
      __syncthreads();   // all waves' partials in LDS (=> all gates passed)

      float s = 0.f;
#pragma unroll
      for (int qq = 0; qq < 8; ++qq) s += lds[qq * 544 + em * 17 + en];
      hval = fast_tanh(s + __uint_as_float(xu));
    }

    // Release path (R13): h stores -> drain -> WG sync -> flag.
    ushort hhi = f2bf(hval);
    ushort hlo = f2bf(hval - bf2f(hhi));
    ushort* hcur = hb + (size_t)((t & 1) * 2) * BH;
    stg2_sc(hcur + eidx, (uint)hhi);
    stg2_sc(hcur + BH + eidx, (uint)hlo);
    asm volatile("s_waitcnt vmcnt(0)" ::: "memory");
    __syncthreads();   // also protects LDS against next step's overwrite
    if (tid == 0) stg4_sc(my_flag, (uint)(t + 1));

    // Off the critical path: fp32 h into d_out (never read by consumers;
    // sc0sc1 reads bypass caches, so this plain store can't serve stale xp).
    out[(size_t)t * BH + eidx] = hval;
  }
}

extern "C" void kernel_launch(void* const* d_in, const int* in_sizes, int n_in,
                              void* d_out, int out_size, void* d_ws, size_t ws_size,
                              hipStream_t stream) {
  const float* x  = (const float*)d_in[0];   // [512][128][512]
  const float* Wx = (const float*)d_in[1];   // [1024][512]
  const float* bx = (const float*)d_in[2];   // [1024]
  const float* Wh = (const float*)d_in[3];   // [1024][1024]
  float* out = (float*)d_out;                // [512][128][1024]
  ushort* ws = (ushort*)d_ws;

  ushort* whh = ws + WS_WHH;
  ushort* whl = ws + WS_WHL;
  ushort* wxh = ws + WS_WXH;
  ushort* wxl = ws + WS_WXL;
  ushort* hb  = ws + WS_HB;                  // [2][2][BH]
  uint* flags   = (uint*)(ws + WS_FLG);      // [4][64]
  uint* xpflags = flags + 256;               // [512][16]

  split_kernel<<<dim3(2048), dim3(256), 0, stream>>>(Wh, Wx, ws, flags);
  fused_kernel<<<dim3(256 + 8192), dim3(512), 0, stream>>>(
      x, wxh, wxl, bx, whh, whl, hb, out, flags, xpflags);
}

// Round 17
// 3468.468 us; speedup vs baseline: 1.6607x; 1.4429x over previous
//
#include <hip/hip_runtime.h>
#include <math.h>

// RNN: L=512, B=128, D=512, H=1024, fp32 in/out.
//   xproj = x @ Wx^T + bx -> d_out;  h_t = tanh(xp_t + h_{t-1} @ Wh^T) in place.
// Precision: split-bf16 (hi+lo), 3 MFMAs per product => ~fp32 accuracy.
// Round 17 = R13 recurrence VERBATIM (champion: 3,010us; R16 fusion regressed
// -- co-resident xproj blocks steal issue slots from the latency chain,
// 5,370us steady-state) + xproj retiled BN 64->256:
//   - same 4 A-row on-the-fly splits now feed 48 MFMAs/chunk (was 24)
//     -> split-VALU per MFMA halves (xproj was VALU-bound ~350 TF class)
//   - x re-read 16x -> 4x (2.1 GB -> 536 MB)

#define L_SEQ 512
#define B_SZ  128
#define D_SZ  512
#define H_SZ  1024
#define BH    (B_SZ * H_SZ)   // 131072

typedef __bf16 bf16x8 __attribute__((ext_vector_type(8)));
typedef float  f32x4  __attribute__((ext_vector_type(4)));
typedef unsigned int uint;
typedef unsigned short ushort;

union V8 { bf16x8 b; ushort u[8]; uint w[4]; };

__device__ __forceinline__ ushort f2bf(float f) {
  uint u = __float_as_uint(f);
  u += 0x7FFFu + ((u >> 16) & 1u);   // round-to-nearest-even
  return (ushort)(u >> 16);
}
__device__ __forceinline__ float bf2f(ushort s) {
  return __uint_as_float(((uint)s) << 16);
}

// tanh(x) = 1 - 2/(e^{2x}+1); v_exp_f32(2^x) + v_rcp_f32. Saturates right.
__device__ __forceinline__ float fast_tanh(float x) {
  float e;
  asm("v_exp_f32 %0, %1" : "=v"(e) : "v"(x * 2.885390081777927f));
  float r;
  asm("v_rcp_f32 %0, %1" : "=v"(r) : "v"(e + 1.0f));
  return 1.0f - 2.0f * r;
}

// Agent-scope (sc0 sc1): bypass L1+L2, coherent at the L3 point. PROVEN (R8).
__device__ __forceinline__ void ldg16_sc(bf16x8& d, const ushort* p) {
  asm volatile("global_load_dwordx4 %0, %1, off sc0 sc1"
               : "=v"(d) : "v"(p) : "memory");
}
__device__ __forceinline__ void stg2_sc(ushort* p, uint v) {
  asm volatile("global_store_short %0, %1, off sc0 sc1"
               :: "v"(p), "v"(v) : "memory");
}
__device__ __forceinline__ void stg4_sc(uint* p, uint v) {
  asm volatile("global_store_dword %0, %1, off sc0 sc1"
               :: "v"(p), "v"(v) : "memory");
}

// ---- d_ws layout (ushort elements unless noted) ----
#define WS_WHH 0            // [1024][1024]
#define WS_WHL 1048576      // [1024][1024]
#define WS_WXH 2097152      // [1024][512]
#define WS_WXL 2621440      // [1024][512]
#define WS_HB  3145728      // [2 parity][2 hi/lo][BH] ushort
#define WS_CNT 3670016      // flags: [4 mb][64 nb] u32 (zeroed per launch)

// Split fp32 weights into bf16 hi + bf16 lo(residual); zero flags.
__global__ void split_kernel(const float* __restrict__ Wh,
                             const float* __restrict__ Wx,
                             ushort* __restrict__ ws,
                             uint* __restrict__ flags) {
  if (blockIdx.x == 0) {
    for (int i = threadIdx.x; i < 512; i += 256) flags[i] = 0u;
  }
  const int total = 1048576 + 524288;
  for (int i = blockIdx.x * blockDim.x + threadIdx.x; i < total;
       i += gridDim.x * blockDim.x) {
    const float* src; ushort *dh, *dl; int j;
    if (i < 1048576) { src = Wh; dh = ws + WS_WHH; dl = ws + WS_WHL; j = i; }
    else             { src = Wx; dh = ws + WS_WXH; dl = ws + WS_WXL; j = i - 1048576; }
    float v = src[j];
    ushort h = f2bf(v);
    dh[j] = h;
    dl[j] = f2bf(v - bf2f(h));
  }
}

// xproj v2: out[m][n] = sum_d x[m][d]*Wx[n][d] + bx[n].
// BM=128, BN=256; 2048 blocks x 512 thr (8 waves, 2M x 4N, wave tile 64x64).
// Per K-chunk: 4 A-row splits feed 48 MFMAs (split-VALU per MFMA halved vs
// BN=64), x re-read 4x instead of 16x.
__global__ __launch_bounds__(512) void xproj_kernel(
    const float* __restrict__ x,             // [65536][512]
    const ushort* __restrict__ wxh,          // [1024][512]
    const ushort* __restrict__ wxl,
    const float* __restrict__ bx,            // [1024]
    float* __restrict__ out)                 // [65536][1024]
{
  const int bid = blockIdx.x;
  const int bn = bid & 3;        // 4 N-blocks of 256 (fastest: share x rows)
  const int bm = bid >> 2;       // 512 M-blocks of 128
  const int tid = threadIdx.x;
  const int w = tid >> 6, l = tid & 63;
  const int wm = w & 1, wn = w >> 1;         // 2(M) x 4(N) waves
  const int lr = l & 15, lk = (l >> 4) * 8;
  const int mbase = bm * 128 + wm * 64;
  const int nbase = bn * 256 + wn * 64;

  f32x4 acc[4][4] = {};

  for (int k0 = 0; k0 < 512; k0 += 32) {
    bf16x8 ah[4], al[4], bh[4], bl[4];
#pragma unroll
    for (int i = 0; i < 4; ++i) {
      const float* ap = x + (size_t)(mbase + i * 16 + lr) * 512 + k0 + lk;
      float4 v0 = *reinterpret_cast<const float4*>(ap);
      float4 v1 = *reinterpret_cast<const float4*>(ap + 4);
      float vv[8] = {v0.x, v0.y, v0.z, v0.w, v1.x, v1.y, v1.z, v1.w};
      V8 hh, ll;
#pragma unroll
      for (int e = 0; e < 8; ++e) {
        ushort hb = f2bf(vv[e]);
        hh.u[e] = hb;
        ll.u[e] = f2bf(vv[e] - bf2f(hb));
      }
      ah[i] = hh.b; al[i] = ll.b;
    }
#pragma unroll
    for (int j = 0; j < 4; ++j) {
      size_t boff = (size_t)(nbase + j * 16 + lr) * 512 + k0 + lk;
      bh[j] = *reinterpret_cast<const bf16x8*>(wxh + boff);
      bl[j] = *reinterpret_cast<const bf16x8*>(wxl + boff);
    }
#pragma unroll
    for (int i = 0; i < 4; ++i)
#pragma unroll
      for (int j = 0; j < 4; ++j) {
        acc[i][j] = __builtin_amdgcn_mfma_f32_16x16x32_bf16(ah[i], bh[j], acc[i][j], 0, 0, 0);
        acc[i][j] = __builtin_amdgcn_mfma_f32_16x16x32_bf16(ah[i], bl[j], acc[i][j], 0, 0, 0);
        acc[i][j] = __builtin_amdgcn_mfma_f32_16x16x32_bf16(al[i], bh[j], acc[i][j], 0, 0, 0);
      }
  }

  // Epilogue. C/D layout: col = lane&15, row = (lane>>4)*4 + r.
#pragma unroll
  for (int j = 0; j < 4; ++j) {
    int n = nbase + j * 16 + lr;
    float bxv = bx[n];
#pragma unroll
    for (int i = 0; i < 4; ++i)
#pragma unroll
      for (int r = 0; r < 4; ++r) {
        int m = mbase + i * 16 + (l >> 4) * 4 + r;
        out[(size_t)m * 1024 + n] = acc[i][j][r] + bxv;
      }
  }
}

// Persistent recurrence — R13 VERBATIM (champion protocol).
// 256 WGs x 512 threads. WG (mb,nb): rows [mb*32,+32) x cols [nb*16,+16).
// Wave q owns K-slice [q*128,+128); Wh frags in registers throughout.
// Gate: wave q at step t waits flag[mb][8q+p] >= t for p=0..7. Flags publish
// after h-store drain (vmcnt(0)+__syncthreads) -> flag seen => h visible.
__global__ __launch_bounds__(512, 2) void rnn_persistent(
    const ushort* __restrict__ whh,  // [1024][1024]
    const ushort* __restrict__ whl,
    ushort* __restrict__ hb,         // [2 parity][2 hi/lo][BH]
    float* __restrict__ out,         // [512][BH] (xproj in, h out)
    uint* __restrict__ flags)        // [4][64]
{
  __shared__ float lds[8 * 32 * 17];         // 17408 B, stride-17 pad
  const int wg = blockIdx.x;                 // 0..255
  const int xc = wg & 7, yy = wg >> 3;
  const int mb = xc & 3;
  const int nb = ((xc >> 2) << 5) + yy;      // 0..63
  const int tid = threadIdx.x;
  const int q = tid >> 6;                    // k-slice 0..7
  const int l = tid & 63;
  const int lr = l & 15, lk = (l >> 4) * 8;
  const int kbase = q * 128 + lk;
  const int row0 = (l >> 4) * 4;

  const ushort* bph = whh + (size_t)(nb * 16 + lr) * 1024 + kbase;
  const ushort* bpl = whl + (size_t)(nb * 16 + lr) * 1024 + kbase;
  bf16x8 vBh[4], vBl[4];
#pragma unroll
  for (int kb = 0; kb < 4; ++kb) {
    vBh[kb] = *reinterpret_cast<const bf16x8*>(bph + kb * 32);
    vBl[kb] = *reinterpret_cast<const bf16x8*>(bpl + kb * 32);
  }

  const size_t aoff = (size_t)(mb * 32 + lr) * 1024 + kbase;
  const ushort* planeA0 = hb + aoff;            // parity 0 hi
  const ushort* planeA1 = hb + 2 * BH + aoff;   // parity 1 hi

  const int em = tid >> 4, en = tid & 15;
  const size_t eidx = (size_t)(mb * 32 + em) * 1024 + nb * 16 + en;

  const uint* gate_ptr = flags + (mb << 6) + (q << 3) + (l & 7);
  uint* my_flag = flags + (mb << 6) + nb;

  for (int t = 0; t < L_SEQ; ++t) {
    float* xpt = out + (size_t)t * BH;
    const float xpv = xpt[eidx];             // prefetch; overlaps gate wait
    float hval;

    if (t > 0) {
      const uint tgt = (uint)t;
      for (uint spin = 0; spin < (1u << 20); ++spin) {
        uint f;
        asm volatile("global_load_dword %0, %1, off sc0 sc1\n\t"
                     "s_waitcnt vmcnt(0)"
                     : "=v"(f) : "v"(gate_ptr) : "memory");
        if (__all((int)(f >= tgt))) break;
        __builtin_amdgcn_s_sleep(1);
      }
      __builtin_amdgcn_sched_barrier(0);     // nothing drifts above the gate

      const ushort* ah = ((t - 1) & 1) ? planeA1 : planeA0;
      const ushort* al = ah + BH;
      bf16x8 vA0h[4], vA0l[4], vA1h[4], vA1l[4];
#pragma unroll
      for (int kb = 0; kb < 4; ++kb) {
        const int ko = kb * 32;
        ldg16_sc(vA0h[kb], ah + ko);
        ldg16_sc(vA0l[kb], al + ko);
        ldg16_sc(vA1h[kb], ah + 16 * 1024 + ko);
        ldg16_sc(vA1l[kb], al + 16 * 1024 + ko);
      }
      asm volatile("s_waitcnt vmcnt(0)" ::: "memory");
      __builtin_amdgcn_sched_barrier(0);     // rule #18: no consumer hoists

      f32x4 acc0 = {0.f, 0.f, 0.f, 0.f};
      f32x4 acc1 = {0.f, 0.f, 0.f, 0.f};
#pragma unroll
      for (int kb = 0; kb < 4; ++kb) {
        acc0 = __builtin_amdgcn_mfma_f32_16x16x32_bf16(vA0h[kb], vBh[kb], acc0, 0, 0, 0);
        acc1 = __builtin_amdgcn_mfma_f32_16x16x32_bf16(vA1h[kb], vBh[kb], acc1, 0, 0, 0);
        acc0 = __builtin_amdgcn_mfma_f32_16x16x32_bf16(vA0h[kb], vBl[kb], acc0, 0, 0, 0);
        acc1 = __builtin_amdgcn_mfma_f32_16x16x32_bf16(vA1h[kb], vBl[kb], acc1, 0, 0, 0);
        acc0 = __builtin_amdgcn_mfma_f32_16x16x32_bf16(vA0l[kb], vBh[kb], acc0, 0, 0, 0);
        acc1 = __builtin_amdgcn_mfma_f32_16x16x32_bf16(vA1l[kb], vBh[kb], acc1, 0, 0, 0);
      }

      // Partials -> LDS. C/D layout: col = lane&15, row = (lane>>4)*4 + r.
#pragma unroll
      for (int r = 0; r < 4; ++r) {
        lds[q * 544 + (row0 + r) * 17 + lr]      = acc0[r];
        lds[q * 544 + (16 + row0 + r) * 17 + lr] = acc1[r];
      }
      __syncthreads();   // all waves' partials in LDS (=> all gates passed)

      float s = 0.f;
#pragma unroll
      for (int qq = 0; qq < 8; ++qq) s += lds[qq * 544 + em * 17 + en];
      hval = fast_tanh(s + xpv);
    } else {
      hval = fast_tanh(xpv);
    }

    // Release path: bf16 hi/lo stores -> drain -> WG sync -> flag.
    ushort hhi = f2bf(hval);
    ushort hlo = f2bf(hval - bf2f(hhi));
    ushort* hcur = hb + (size_t)((t & 1) * 2) * BH;
    stg2_sc(hcur + eidx, (uint)hhi);
    stg2_sc(hcur + BH + eidx, (uint)hlo);
    asm volatile("s_waitcnt vmcnt(0)" ::: "memory");
    __syncthreads();   // also protects LDS against next step's overwrite
    if (tid == 0) stg4_sc(my_flag, (uint)(t + 1));

    // Off the critical path: fp32 h into d_out (never read by consumers).
    xpt[eidx] = hval;
  }
}

extern "C" void kernel_launch(void* const* d_in, const int* in_sizes, int n_in,
                              void* d_out, int out_size, void* d_ws, size_t ws_size,
                              hipStream_t stream) {
  const float* x  = (const float*)d_in[0];   // [512][128][512]
  const float* Wx = (const float*)d_in[1];   // [1024][512]
  const float* bx = (const float*)d_in[2];   // [1024]
  const float* Wh = (const float*)d_in[3];   // [1024][1024]
  float* out = (float*)d_out;                // [512][128][1024]
  ushort* ws = (ushort*)d_ws;

  ushort* whh = ws + WS_WHH;
  ushort* whl = ws + WS_WHL;
  ushort* wxh = ws + WS_WXH;
  ushort* wxl = ws + WS_WXL;
  ushort* hb  = ws + WS_HB;                  // [2][2][BH]
  uint* flags = (uint*)(ws + WS_CNT);

  split_kernel<<<dim3(2048), dim3(256), 0, stream>>>(Wh, Wx, ws, flags);
  xproj_kernel<<<dim3(2048), dim3(512), 0, stream>>>(x, wxh, wxl, bx, out);
  rnn_persistent<<<dim3(256), dim3(512), 0, stream>>>(whh, whl, hb, out, flags);
}